// Round 2
// baseline (616.020 us; speedup 1.0000x reference)
//
#include <hip/hip_runtime.h>
#include <hip/hip_bf16.h>

// ---------- types ----------
typedef unsigned short u16;
typedef __attribute__((ext_vector_type(4))) float f32x4;
typedef __attribute__((ext_vector_type(8))) short short8;   // 8 bf16 for MFMA operands
typedef __attribute__((ext_vector_type(8))) u16 u16x8;

__device__ __forceinline__ f32x4 fzero() { f32x4 z = {0.f, 0.f, 0.f, 0.f}; return z; }

// f32 -> bf16 bits, round-to-nearest-even
__device__ __forceinline__ u16 f2b(float x) {
  unsigned u = __builtin_bit_cast(unsigned, x);
  unsigned r = (u + 0x7fffu + ((u >> 16) & 1u)) >> 16;
  return (u16)r;
}

// ---------- problem constants ----------
#define BS 4096
#define H_ 256
#define A_ 30

// ---------- ws offsets (bytes) ----------
#define OFF_W2B   0UL            // 33,685,504  (2056 slices x 16KB, frag-order layout)
#define OFF_HIDB  33685504UL     //  2,097,152
#define OFF_FWT   35782656UL     //    131,072  (few^T bf16 [h][e])
#define OFF_WIHB  35913728UL     //    393,216
#define OFF_WHHB  36306944UL     //    393,216
#define OFF_H1B   36700160UL     //  2,097,152
#define OFF_XIN   38797312UL     //  4,194,304  f32 (later: yb @+0, WcB @+2MB, bc)
#define OFF_WCB   40894464UL     //    393,216
#define OFF_BCB   41287680UL     //      3,072
#define OFF_PART  42991616UL     // 33,554,432  (later: gim @+0, ghm @+12,582,912)
// end = 76,546,048

// convert chunk counts (8 elems per chunk)
#define NC_W2   2105344L
#define NC_HID  131072L
#define NC_FET  8192L
#define NC_WIH  24576L
#define NC_WHH  24576L
// total = 2,293,760 chunks -> 8960 blocks
#define NB_CONV 8960
#define NB_PRE  (NB_CONV + 4096 + 4096)   // + ln1 + h1 = 17152

// ================= block-wide mean/inv-std over 256 elems (256 thr) =================
__device__ __forceinline__ void blk_ln(float v, float* red, int t, float& mu, float& inv) {
  float s = v, sq = v * v;
  #pragma unroll
  for (int o = 32; o; o >>= 1) { s += __shfl_xor(s, o); sq += __shfl_xor(sq, o); }
  int w = t >> 6;
  if ((t & 63) == 0) { red[w] = s; red[4 + w] = sq; }
  __syncthreads();
  float S = red[0] + red[1] + red[2] + red[3];
  float Q = red[4] + red[5] + red[6] + red[7];
  mu = S * (1.f / 256.f);
  float var = Q * (1.f / 256.f) - mu * mu;
  inv = rsqrtf(var + 1e-5f);
  __syncthreads();
}

// ================= k_pre: convert + ln1 + h1 (one launch, independent segments) ==========
// w2b layout (dest-coalesced write): dst[((i*8+ks)*256 + h)*32 + kk] = hy_w2[i*256+h][ks*32+kk]
// so slice s=(i*8+ks) is a 16KB blob in exact per-lane MFMA-fragment order.
__global__ void k_pre(const float* __restrict__ hyw2, const float* __restrict__ hid,
                      const float* __restrict__ few,  const float* __restrict__ wih,
                      const float* __restrict__ whh,
                      const float* __restrict__ inp,  const float* __restrict__ ln1g,
                      const float* __restrict__ ln1b,
                      const float* __restrict__ goal, const float* __restrict__ hyw1,
                      const float* __restrict__ hyb1,
                      u16* __restrict__ w2b, u16* __restrict__ hidb, u16* __restrict__ fwbT,
                      u16* __restrict__ wihb, u16* __restrict__ whhb,
                      float* __restrict__ xin, u16* __restrict__ h1b) {
  const int bx = blockIdx.x, t = threadIdx.x;
  __shared__ float sm[64];   // ln1: red[8]; h1: goal row[64]

  if (bx < NB_CONV) {
    long c = (long)bx * 256 + t;
    if (c < NC_W2) {
      long d = c * 8;
      int kk0 = (int)((c & 3) * 8);
      int h   = (int)((c >> 2) & 255);
      long s  = c >> 10;               // slice 0..2055
      int ks  = (int)(s & 7);
      long i  = s >> 3;                // 0..256 (i==256 -> bias rows 65536+h)
      const float* src = hyw2 + (i * 256 + h) * 256 + ks * 32 + kk0;
      f32x4 a = *(const f32x4*)src;
      f32x4 b = *(const f32x4*)(src + 4);
      u16x8 o;
      o[0]=f2b(a[0]); o[1]=f2b(a[1]); o[2]=f2b(a[2]); o[3]=f2b(a[3]);
      o[4]=f2b(b[0]); o[5]=f2b(b[1]); o[6]=f2b(b[2]); o[7]=f2b(b[3]);
      *(u16x8*)(w2b + d) = o;
      return;
    }
    c -= NC_W2;
    const float* src = nullptr; u16* dst = nullptr;
    if (c < NC_HID) { src = hid; dst = hidb; }
    else {
      c -= NC_HID;
      if (c < NC_FET) {   // few^T gather: fwbT[h][e] = few[e][h]
        long d = c * 8;
        int h = (int)(c >> 5), e0 = (int)((c & 31) * 8);
        u16x8 o;
        #pragma unroll
        for (int j = 0; j < 8; ++j) o[j] = f2b(few[(long)(e0 + j) * 256 + h]);
        *(u16x8*)(fwbT + d) = o;
        return;
      }
      c -= NC_FET;
      if (c < NC_WIH) { src = wih; dst = wihb; }
      else { c -= NC_WIH; src = whh; dst = whhb; }
    }
    long e = c * 8;
    f32x4 a = *(const f32x4*)(src + e);
    f32x4 b = *(const f32x4*)(src + e + 4);
    u16x8 o;
    o[0]=f2b(a[0]); o[1]=f2b(a[1]); o[2]=f2b(a[2]); o[3]=f2b(a[3]);
    o[4]=f2b(b[0]); o[5]=f2b(b[1]); o[6]=f2b(b[2]); o[7]=f2b(b[3]);
    *(u16x8*)(dst + e) = o;
    return;
  }

  if (bx < NB_CONV + 4096) {           // ---- ln1 ----
    int bb = bx - NB_CONV;
    float v = inp[(long)bb * 256 + t];
    float mu, inv; blk_ln(v, sm, t, mu, inv);
    xin[(long)bb * 256 + t] = (v - mu) * inv * ln1g[t] + ln1b[t];
    return;
  }

  // ---- h1 (f32): h1[b,e] = relu(sum_g goal[b,g]*hyw1[e,g] + b1[e]) -> bf16 ----
  {
    int bb = bx - (NB_CONV + 4096);
    if (t < 64) sm[t] = goal[(long)bb * 64 + t];
    __syncthreads();
    const float* wr = hyw1 + (long)t * 64;
    float acc = hyb1[t];
    #pragma unroll
    for (int g4 = 0; g4 < 16; ++g4) {
      f32x4 w = *(const f32x4*)(wr + g4 * 4);
      acc = fmaf(sm[g4*4+0], w[0], acc);
      acc = fmaf(sm[g4*4+1], w[1], acc);
      acc = fmaf(sm[g4*4+2], w[2], acc);
      acc = fmaf(sm[g4*4+3], w[3], acc);
    }
    h1b[(long)bb * 256 + t] = f2b(fmaxf(acc, 0.f));
  }
}

// ================= k_big: barrier-free fused hypernet GEMM + tanh*3 + contraction ==========
// grid 512 = 64 btiles x 8 islices (islice = bx&7 -> XCD-pinned 4.2MB w2 chunk).
// B (w2) streams global->VGPR directly (frag-order layout, coalesced), 4-deep prefetch.
// A (h1 64x256 tile) + xin slice resident in LDS; ONE barrier total.
__global__ __launch_bounds__(256, 2) void k_big(const u16* __restrict__ w2b,
                                                const u16* __restrict__ h1b,
                                                const float* __restrict__ xin,
                                                const float* __restrict__ b2,
                                                float* __restrict__ part) {
  const int bx = blockIdx.x;
  const int islice = bx & 7, btile = bx >> 3;
  const int b0 = btile * 64, i0 = islice * 32;
  const int ni = (islice == 7) ? 33 : 32;   // islice 7 adds the bias row-block (i==256)
  const int t = threadIdx.x, lane = t & 63, wid = t >> 6;
  const int la = lane & 15, lb = lane >> 4;
  const int c0 = wid * 64;

  __shared__ u16 As[64 * 264];      // h1 tile, pitch 264 (even 16B-slot spread)
  __shared__ float xs[32][64];      // xin slice [ii][row]

  #pragma unroll
  for (int j = 0; j < 8; ++j) {
    int q = t + 256 * j;
    int row = q >> 5, cc = q & 31;
    *(u16x8*)&As[row * 264 + cc * 8] = *(const u16x8*)(h1b + (long)(b0 + row) * 256 + cc * 8);
  }
  {
    int row = t >> 2, part4 = t & 3;
    const float* src = xin + (long)(b0 + row) * 256 + i0 + part4 * 8;
    f32x4 v0 = *(const f32x4*)src;
    f32x4 v1 = *(const f32x4*)(src + 4);
    #pragma unroll
    for (int j = 0; j < 4; ++j) xs[part4 * 8 + j][row] = v0[j];
    #pragma unroll
    for (int j = 0; j < 4; ++j) xs[part4 * 8 + 4 + j][row] = v1[j];
  }
  __syncthreads();   // the only barrier

  const u16* bptr = w2b + (long)i0 * 8 * 8192 + (c0 + la) * 32 + lb * 8;
  const int lds_a = la * 528 + lb * 16;   // byte offset into As

  f32x4 accT[4][4];
  #pragma unroll
  for (int m = 0; m < 4; ++m)
    #pragma unroll
    for (int n = 0; n < 4; ++n) accT[m][n] = fzero();

  short8 bf[4][4];   // [slot ks&3][n] — 4-deep prefetch ring
  #pragma unroll
  for (int s = 0; s < 4; ++s)
    #pragma unroll
    for (int n = 0; n < 4; ++n)
      bf[s][n] = *(const short8*)(bptr + (long)s * 8192 + n * 512);

  for (int ii = 0; ii < ni; ++ii) {
    f32x4 cf[4][4];
    #pragma unroll
    for (int ks = 0; ks < 8; ++ks) {
      const int s = ii * 8 + ks;
      short8 af[4];
      #pragma unroll
      for (int m = 0; m < 4; ++m)
        af[m] = *(const short8*)((const char*)As + lds_a + m * 8448 + ks * 64);
      if (ks == 0) {
        #pragma unroll
        for (int m = 0; m < 4; ++m)
          #pragma unroll
          for (int n = 0; n < 4; ++n)
            cf[m][n] = __builtin_amdgcn_mfma_f32_16x16x32_bf16(af[m], bf[ks & 3][n], fzero(), 0, 0, 0);
      } else {
        #pragma unroll
        for (int m = 0; m < 4; ++m)
          #pragma unroll
          for (int n = 0; n < 4; ++n)
            cf[m][n] = __builtin_amdgcn_mfma_f32_16x16x32_bf16(af[m], bf[ks & 3][n], cf[m][n], 0, 0, 0);
      }
      // prefetch s+4 into the slot just consumed (reads past NST stay inside ws — harmless)
      #pragma unroll
      for (int n = 0; n < 4; ++n)
        bf[ks & 3][n] = *(const short8*)(bptr + (long)(s + 4) * 8192 + n * 512);
    }
    // epilogue: w = 3*tanh(pre) (odd poly, |pre| small), accT += xin[b,i] * w
    const int ig = i0 + ii;
    const bool isb = (ig == 256);
    f32x4 xv[4];
    if (isb) {
      #pragma unroll
      for (int m = 0; m < 4; ++m) { f32x4 o = {1.f,1.f,1.f,1.f}; xv[m] = o; }
    } else {
      #pragma unroll
      for (int m = 0; m < 4; ++m)
        xv[m] = *(const f32x4*)&xs[ii][m * 16 + lb * 4];
    }
    float b2v[4];
    #pragma unroll
    for (int n = 0; n < 4; ++n)
      b2v[n] = b2[(long)ig * 256 + c0 + n * 16 + la];
    #pragma unroll
    for (int m = 0; m < 4; ++m)
      #pragma unroll
      for (int n = 0; n < 4; ++n)
        #pragma unroll
        for (int r = 0; r < 4; ++r) {
          float pre = cf[m][n][r] + b2v[n];
          float t2 = pre * pre;
          float w = pre * fmaf(t2, fmaf(t2, fmaf(t2, -0.161905f, 0.4f), -1.0f), 3.0f);
          accT[m][n][r] = fmaf(xv[m][r], w, accT[m][n][r]);
        }
  }

  float* dst = part + (long)islice * (4096 * 256);
  #pragma unroll
  for (int m = 0; m < 4; ++m)
    #pragma unroll
    for (int n = 0; n < 4; ++n)
      #pragma unroll
      for (int r = 0; r < 4; ++r)
        dst[(long)(b0 + m * 16 + lb * 4 + r) * 256 + (c0 + n * 16 + la)] = accT[m][n][r];
}

// ================= k_mid: redln (sum partials + LN2 + relu -> bf16) + Wc + bc ==========
__global__ void k_mid(const float* __restrict__ part, const float* __restrict__ g,
                      const float* __restrict__ b, u16* __restrict__ yb,
                      const float* __restrict__ wihf, const float* __restrict__ few,
                      u16* __restrict__ wcb,
                      const float* __restrict__ bih, const float* __restrict__ feb,
                      float* __restrict__ bcb) {
  const int bx = blockIdx.x, t = threadIdx.x;
  __shared__ float sm[256];
  if (bx < 4096) {                      // ---- redln ----
    float s = 0.f;
    #pragma unroll
    for (int sl = 0; sl < 8; ++sl) s += part[(long)sl * (4096 * 256) + (long)bx * 256 + t];
    float mu, inv; blk_ln(s, sm, t, mu, inv);
    float v = (s - mu) * inv * g[t] + b[t];
    yb[(long)bx * 256 + t] = f2b(fmaxf(v, 0.f));
    return;
  }
  if (bx < 4096 + 768) {                // ---- Wc[g,h] = sum_e wih[g,e]*few[e,h] -> bf16 ----
    int gg = bx - 4096;
    sm[t] = wihf[(long)gg * 256 + t];
    __syncthreads();
    float acc = 0.f;
    #pragma unroll 8
    for (int e = 0; e < 256; ++e) acc = fmaf(sm[e], few[(long)e * 256 + t], acc);
    wcb[(long)gg * 256 + t] = f2b(acc);
    return;
  }
  {                                     // ---- bc[g] = bih[g] + wih[g,:]·feb ----
    int gg = (bx - 4864) * 256 + t;
    float acc = bih[gg];
    const float* wr = wihf + (long)gg * 256;
    #pragma unroll 8
    for (int e = 0; e < 256; ++e) acc = fmaf(wr[e], feb[e], acc);
    bcb[gg] = acc;
  }
}

// ================= gemm256: C[M][N](f32) = A[M][256] @ B[N][256]^T + bias ==========
// 128x128 tile, K staged in two 128-halves (LDS 69.6KB -> 2 blocks/CU)
__device__ __forceinline__ void gemm256(const u16* __restrict__ Ab, const u16* __restrict__ Bb,
                                        const float* __restrict__ bias, float* __restrict__ Cf,
                                        int N, int ntiles, int blk, u16* As, u16* Bs) {
  const int t = threadIdx.x;
  const int mt = blk / ntiles, nt = blk % ntiles;
  const int m0 = mt * 128, n0 = nt * 128;
  const int lane = t & 63, wid = t >> 6;
  const int la = lane & 15, lb = lane >> 4;
  const int r0 = (wid >> 1) * 64, c0 = (wid & 1) * 64;
  f32x4 acc[4][4];
  #pragma unroll
  for (int m = 0; m < 4; ++m)
    #pragma unroll
    for (int n = 0; n < 4; ++n) acc[m][n] = fzero();
  for (int kh = 0; kh < 2; ++kh) {
    #pragma unroll
    for (int j = 0; j < 8; ++j) {
      int q = t + 256 * j;            // 0..2047: row=q>>4, chunk=q&15
      int row = q >> 4, cc = q & 15;
      *(u16x8*)&As[row * 136 + cc * 8] = *(const u16x8*)(Ab + (long)(m0 + row) * 256 + kh * 128 + cc * 8);
      *(u16x8*)&Bs[row * 136 + cc * 8] = *(const u16x8*)(Bb + (long)(n0 + row) * 256 + kh * 128 + cc * 8);
    }
    __syncthreads();
    #pragma unroll
    for (int ks = 0; ks < 4; ++ks) {
      short8 af[4], bf[4];
      #pragma unroll
      for (int m = 0; m < 4; ++m) af[m] = *(const short8*)&As[(r0 + m * 16 + la) * 136 + ks * 32 + lb * 8];
      #pragma unroll
      for (int n = 0; n < 4; ++n) bf[n] = *(const short8*)&Bs[(c0 + n * 16 + la) * 136 + ks * 32 + lb * 8];
      #pragma unroll
      for (int m = 0; m < 4; ++m)
        #pragma unroll
        for (int n = 0; n < 4; ++n)
          acc[m][n] = __builtin_amdgcn_mfma_f32_16x16x32_bf16(af[m], bf[n], acc[m][n], 0, 0, 0);
    }
    __syncthreads();
  }
  #pragma unroll
  for (int n = 0; n < 4; ++n) {
    int gc = n0 + c0 + n * 16 + la;
    float bv = bias[gc];
    #pragma unroll
    for (int m = 0; m < 4; ++m) {
      int gr = m0 + r0 + m * 16 + lb * 4;
      #pragma unroll
      for (int r = 0; r < 4; ++r)
        Cf[(long)(gr + r) * N + gc] = acc[m][n][r] + bv;
    }
  }
}

// ================= k_gigh: gi = yb@Wc^T + bc ; gh = hidb@whh^T + bhh ==========
__global__ __launch_bounds__(256) void k_gigh(const u16* __restrict__ yb, const u16* __restrict__ wcb,
                                              const float* __restrict__ bcb,
                                              const u16* __restrict__ hidb, const u16* __restrict__ whhb,
                                              const float* __restrict__ bhh,
                                              float* __restrict__ gim, float* __restrict__ ghm) {
  __shared__ u16 smem[2 * 128 * 136];
  const int bx = blockIdx.x;
  if (bx < 192) gemm256(yb,   wcb,  bcb, gim, 768, 6, bx,       smem, smem + 128 * 136);
  else          gemm256(hidb, whhb, bhh, ghm, 768, 6, bx - 192, smem, smem + 128 * 136);
}

// ================= k_gru: GRU cell + dueling heads =================
__global__ void k_gru(const float* __restrict__ gi, const float* __restrict__ gh,
                      const float* __restrict__ hin,
                      const float* __restrict__ vw, const float* __restrict__ vb,
                      const float* __restrict__ aw, const float* __restrict__ ab,
                      float* __restrict__ qout, float* __restrict__ hout) {
  int bb = blockIdx.x, t = threadIdx.x;
  const float* gib = gi + (long)bb * 768;
  const float* ghb = gh + (long)bb * 768;
  float ir = gib[t], iz = gib[256 + t], inx = gib[512 + t];
  float hr = ghb[t], hz = ghb[256 + t], hn = ghb[512 + t];
  float hprev = hin[(long)bb * 256 + t];
  float r = 1.f / (1.f + expf(-(ir + hr)));
  float z = 1.f / (1.f + expf(-(iz + hz)));
  float n = tanhf(inx + r * hn);
  float h = (1.f - z) * n + z * hprev;
  hout[(long)bb * 256 + t] = h;
  __shared__ float hl[256];
  __shared__ float ov[32];
  __shared__ float mred;
  hl[t] = h;
  __syncthreads();
  int gidx = t >> 3, lg = t & 7;
  if (gidx < 31) {
    const float* wr = (gidx < 30) ? (aw + (long)gidx * 256) : vw;
    float p = 0.f;
    #pragma unroll 8
    for (int j = 0; j < 32; ++j) p += hl[lg + 8 * j] * wr[lg + 8 * j];
    p += __shfl_xor(p, 1); p += __shfl_xor(p, 2); p += __shfl_xor(p, 4);
    if (lg == 0) ov[gidx] = p + ((gidx < 30) ? ab[gidx] : vb[0]);
  }
  __syncthreads();
  if (t == 0) {
    float m = 0.f;
    #pragma unroll
    for (int a = 0; a < 30; ++a) m += ov[a];
    mred = m * (1.f / 30.f);
  }
  __syncthreads();
  if (t < 30) qout[(long)bb * 30 + t] = ov[30] + ov[t] - mred;
}

// ================= launch =================
extern "C" void kernel_launch(void* const* d_in, const int* in_sizes, int n_in,
                              void* d_out, int out_size, void* d_ws, size_t ws_size,
                              hipStream_t stream) {
  const float* inputs = (const float*)d_in[0];
  const float* hidden = (const float*)d_in[1];
  const float* goal   = (const float*)d_in[2];
  const float* ln1g   = (const float*)d_in[3];
  const float* ln1b   = (const float*)d_in[4];
  const float* hyw1   = (const float*)d_in[5];
  const float* hyb1   = (const float*)d_in[6];
  const float* hyw2   = (const float*)d_in[7];
  const float* hyb2   = (const float*)d_in[8];
  const float* ln2g   = (const float*)d_in[9];
  const float* ln2b   = (const float*)d_in[10];
  const float* few    = (const float*)d_in[11];
  const float* feb    = (const float*)d_in[12];
  const float* wih    = (const float*)d_in[13];
  const float* whh    = (const float*)d_in[14];
  const float* bih    = (const float*)d_in[15];
  const float* bhh    = (const float*)d_in[16];
  const float* valw   = (const float*)d_in[17];
  const float* valb   = (const float*)d_in[18];
  const float* advw   = (const float*)d_in[19];
  const float* advb   = (const float*)d_in[20];

  char* ws = (char*)d_ws;
  u16* w2b   = (u16*)(ws + OFF_W2B);
  u16* hidb  = (u16*)(ws + OFF_HIDB);
  u16* fwbT  = (u16*)(ws + OFF_FWT);
  u16* wihb  = (u16*)(ws + OFF_WIHB);   // kept converted (unused by new path but cheap) — actually used? no; keep slot
  u16* whhb  = (u16*)(ws + OFF_WHHB);
  u16* h1b   = (u16*)(ws + OFF_H1B);
  float* xin = (float*)(ws + OFF_XIN);
  u16* yb    = (u16*)(ws + OFF_XIN);                 // aliases xin (dead after k_big)
  u16* wcb   = (u16*)(ws + OFF_WCB);
  float* bcb = (float*)(ws + OFF_BCB);
  float* prt = (float*)(ws + OFF_PART);
  float* gim = (float*)(ws + OFF_PART);              // aliases part (dead after k_mid)
  float* ghm = (float*)(ws + OFF_PART + 12582912UL);
  float* qout = (float*)d_out;
  float* hout = qout + (long)BS * A_;

  k_pre<<<NB_PRE, 256, 0, stream>>>(hyw2, hidden, few, wih, whh,
                                    inputs, ln1g, ln1b, goal, hyw1, hyb1,
                                    w2b, hidb, fwbT, wihb, whhb, xin, h1b);
  k_big<<<512, 256, 0, stream>>>(w2b, h1b, xin, hyb2, prt);
  k_mid<<<4867, 256, 0, stream>>>(prt, ln2g, ln2b, yb, wih, few, wcb, bih, feb, bcb);
  k_gigh<<<384, 256, 0, stream>>>(yb, wcb, bcb, hidb, whhb, bhh, gim, ghm);
  k_gru<<<4096, 256, 0, stream>>>(gim, ghm, hidden, valw, valb, advw, advb, qout, hout);
}

// Round 3
// 376.127 us; speedup vs baseline: 1.6378x; 1.6378x over previous
//
#include <hip/hip_runtime.h>
#include <hip/hip_bf16.h>

// ---------- types ----------
typedef unsigned short u16;
typedef __attribute__((ext_vector_type(4))) float f32x4;
typedef __attribute__((ext_vector_type(8))) short short8;   // 8 bf16 for MFMA operands
typedef __attribute__((ext_vector_type(8))) u16 u16x8;

__device__ __forceinline__ f32x4 fzero() { f32x4 z = {0.f, 0.f, 0.f, 0.f}; return z; }

// f32 -> bf16 bits, round-to-nearest-even
__device__ __forceinline__ u16 f2b(float x) {
  unsigned u = __builtin_bit_cast(unsigned, x);
  unsigned r = (u + 0x7fffu + ((u >> 16) & 1u)) >> 16;
  return (u16)r;
}

// ---------- problem constants ----------
#define BS 4096
#define H_ 256
#define A_ 30

// ---------- ws offsets (bytes) ----------
#define OFF_W2B   0UL            // 33,685,504  (2056 slices x 16KB, frag-order layout)
#define OFF_HIDB  33685504UL     //  2,097,152
#define OFF_FWT   35782656UL     //    131,072  (few^T bf16 [h][e])
#define OFF_WIHB  35913728UL     //    393,216
#define OFF_WHHB  36306944UL     //    393,216
#define OFF_H1B   36700160UL     //  2,097,152
#define OFF_XIN   38797312UL     //  4,194,304  f32 (later: yb @+0)
#define OFF_WCB   40894464UL     //    393,216
#define OFF_BCB   41287680UL     //      3,072
#define OFF_PART  42991616UL     // 33,554,432  (later: gim @+0, ghm @+12,582,912)
// end = 76,546,048

// convert chunk counts (8 elems per chunk)
#define NC_W2   2105344L
#define NC_HID  131072L
#define NC_FET  8192L
#define NC_WIH  24576L
#define NC_WHH  24576L
#define NB_CONV 8960
#define NB_PRE  (NB_CONV + 4096 + 4096)   // + ln1 + h1 = 17152

// ================= block-wide mean/inv-std over 256 elems (256 thr) =================
__device__ __forceinline__ void blk_ln(float v, float* red, int t, float& mu, float& inv) {
  float s = v, sq = v * v;
  #pragma unroll
  for (int o = 32; o; o >>= 1) { s += __shfl_xor(s, o); sq += __shfl_xor(sq, o); }
  int w = t >> 6;
  if ((t & 63) == 0) { red[w] = s; red[4 + w] = sq; }
  __syncthreads();
  float S = red[0] + red[1] + red[2] + red[3];
  float Q = red[4] + red[5] + red[6] + red[7];
  mu = S * (1.f / 256.f);
  float var = Q * (1.f / 256.f) - mu * mu;
  inv = rsqrtf(var + 1e-5f);
  __syncthreads();
}

// ================= k_pre: convert + ln1 + h1 (one launch, independent segments) ==========
// w2b layout: dst[((i*8+ks)*256 + h)*32 + kk] = hy_w2[i*256+h][ks*32+kk]
// so slice s=(i*8+ks) is a 16KB blob in exact per-lane MFMA-fragment order.
__global__ void k_pre(const float* __restrict__ hyw2, const float* __restrict__ hid,
                      const float* __restrict__ few,  const float* __restrict__ wih,
                      const float* __restrict__ whh,
                      const float* __restrict__ inp,  const float* __restrict__ ln1g,
                      const float* __restrict__ ln1b,
                      const float* __restrict__ goal, const float* __restrict__ hyw1,
                      const float* __restrict__ hyb1,
                      u16* __restrict__ w2b, u16* __restrict__ hidb, u16* __restrict__ fwbT,
                      u16* __restrict__ wihb, u16* __restrict__ whhb,
                      float* __restrict__ xin, u16* __restrict__ h1b) {
  const int bx = blockIdx.x, t = threadIdx.x;
  __shared__ float sm[64];   // ln1: red[8]; h1: goal row[64]

  if (bx < NB_CONV) {
    long c = (long)bx * 256 + t;
    if (c < NC_W2) {
      long d = c * 8;
      int kk0 = (int)((c & 3) * 8);
      int h   = (int)((c >> 2) & 255);
      long s  = c >> 10;               // slice 0..2055
      int ks  = (int)(s & 7);
      long i  = s >> 3;                // 0..256 (i==256 -> bias rows 65536+h)
      const float* src = hyw2 + (i * 256 + h) * 256 + ks * 32 + kk0;
      f32x4 a = *(const f32x4*)src;
      f32x4 b = *(const f32x4*)(src + 4);
      u16x8 o;
      o[0]=f2b(a[0]); o[1]=f2b(a[1]); o[2]=f2b(a[2]); o[3]=f2b(a[3]);
      o[4]=f2b(b[0]); o[5]=f2b(b[1]); o[6]=f2b(b[2]); o[7]=f2b(b[3]);
      *(u16x8*)(w2b + d) = o;
      return;
    }
    c -= NC_W2;
    const float* src = nullptr; u16* dst = nullptr;
    if (c < NC_HID) { src = hid; dst = hidb; }
    else {
      c -= NC_HID;
      if (c < NC_FET) {   // few^T gather: fwbT[h][e] = few[e][h]
        long d = c * 8;
        int h = (int)(c >> 5), e0 = (int)((c & 31) * 8);
        u16x8 o;
        #pragma unroll
        for (int j = 0; j < 8; ++j) o[j] = f2b(few[(long)(e0 + j) * 256 + h]);
        *(u16x8*)(fwbT + d) = o;
        return;
      }
      c -= NC_FET;
      if (c < NC_WIH) { src = wih; dst = wihb; }
      else { c -= NC_WIH; src = whh; dst = whhb; }
    }
    long e = c * 8;
    f32x4 a = *(const f32x4*)(src + e);
    f32x4 b = *(const f32x4*)(src + e + 4);
    u16x8 o;
    o[0]=f2b(a[0]); o[1]=f2b(a[1]); o[2]=f2b(a[2]); o[3]=f2b(a[3]);
    o[4]=f2b(b[0]); o[5]=f2b(b[1]); o[6]=f2b(b[2]); o[7]=f2b(b[3]);
    *(u16x8*)(dst + e) = o;
    return;
  }

  if (bx < NB_CONV + 4096) {           // ---- ln1 ----
    int bb = bx - NB_CONV;
    float v = inp[(long)bb * 256 + t];
    float mu, inv; blk_ln(v, sm, t, mu, inv);
    xin[(long)bb * 256 + t] = (v - mu) * inv * ln1g[t] + ln1b[t];
    return;
  }

  // ---- h1 (f32): h1[b,e] = relu(sum_g goal[b,g]*hyw1[e,g] + b1[e]) -> bf16 ----
  {
    int bb = bx - (NB_CONV + 4096);
    if (t < 64) sm[t] = goal[(long)bb * 64 + t];
    __syncthreads();
    const float* wr = hyw1 + (long)t * 64;
    float acc = hyb1[t];
    #pragma unroll
    for (int g4 = 0; g4 < 16; ++g4) {
      f32x4 w = *(const f32x4*)(wr + g4 * 4);
      acc = fmaf(sm[g4*4+0], w[0], acc);
      acc = fmaf(sm[g4*4+1], w[1], acc);
      acc = fmaf(sm[g4*4+2], w[2], acc);
      acc = fmaf(sm[g4*4+3], w[3], acc);
    }
    h1b[(long)bb * 256 + t] = f2b(fmaxf(acc, 0.f));
  }
}

// ================= k_big: fused hypernet GEMM + tanh*3 + contraction ==========
// grid 512 = 64 btiles x 8 islices (islice = bx&7 -> XCD-pinned 4.2MB w2 chunk).
// B (w2) streams global->VGPR (frag-order layout, coalesced), 4-deep register ring.
// Per-ks RAW s_barrier keeps the block's waves phase-locked (L2 reuse window tight)
// WITHOUT draining vmcnt (loads stay in flight across it). part stored non-temporal
// so it doesn't evict the streaming w2b chunk from the XCD's 4MB L2.
__global__ __launch_bounds__(256, 2) void k_big(const u16* __restrict__ w2b,
                                                const u16* __restrict__ h1b,
                                                const float* __restrict__ xin,
                                                const float* __restrict__ b2,
                                                float* __restrict__ part) {
  const int bx = blockIdx.x;
  const int islice = bx & 7, btile = bx >> 3;
  const int b0 = btile * 64, i0 = islice * 32;
  const int ni = (islice == 7) ? 33 : 32;   // islice 7 adds the bias row-block (i==256)
  const int t = threadIdx.x, lane = t & 63, wid = t >> 6;
  const int la = lane & 15, lb = lane >> 4;
  const int c0 = wid * 64;

  __shared__ u16 As[64 * 264];      // h1 tile, pitch 264 (2-way bank spread = free)
  __shared__ float xs[32][64];      // xin slice [ii][row]

  #pragma unroll
  for (int j = 0; j < 8; ++j) {
    int q = t + 256 * j;
    int row = q >> 5, cc = q & 31;
    *(u16x8*)&As[row * 264 + cc * 8] = *(const u16x8*)(h1b + (long)(b0 + row) * 256 + cc * 8);
  }
  {
    int row = t >> 2, part4 = t & 3;
    const float* src = xin + (long)(b0 + row) * 256 + i0 + part4 * 8;
    f32x4 v0 = *(const f32x4*)src;
    f32x4 v1 = *(const f32x4*)(src + 4);
    #pragma unroll
    for (int j = 0; j < 4; ++j) xs[part4 * 8 + j][row] = v0[j];
    #pragma unroll
    for (int j = 0; j < 4; ++j) xs[part4 * 8 + 4 + j][row] = v1[j];
  }
  __syncthreads();   // init barrier (full drain OK, once)

  const u16* bptr = w2b + (long)i0 * 8 * 8192 + (c0 + la) * 32 + lb * 8;
  const int lds_a = la * 528 + lb * 16;   // byte offset into As

  f32x4 accT[4][4];
  #pragma unroll
  for (int m = 0; m < 4; ++m)
    #pragma unroll
    for (int n = 0; n < 4; ++n) accT[m][n] = fzero();

  short8 bf[4][4];   // [slot ks&3][n] — 4-deep register prefetch ring
  #pragma unroll
  for (int s = 0; s < 4; ++s)
    #pragma unroll
    for (int n = 0; n < 4; ++n)
      bf[s][n] = *(const short8*)(bptr + (long)s * 8192 + n * 512);

  for (int ii = 0; ii < ni; ++ii) {
    f32x4 cf[4][4];
    #pragma unroll
    for (int ks = 0; ks < 8; ++ks) {
      const int s = ii * 8 + ks;
      // rhythm barrier: raw s_barrier, no waitcnt drain — prefetches stay in flight
      __builtin_amdgcn_s_barrier();
      short8 af[4];
      #pragma unroll
      for (int m = 0; m < 4; ++m)
        af[m] = *(const short8*)((const char*)As + lds_a + m * 8448 + ks * 64);
      __builtin_amdgcn_s_setprio(1);
      if (ks == 0) {
        #pragma unroll
        for (int m = 0; m < 4; ++m)
          #pragma unroll
          for (int n = 0; n < 4; ++n)
            cf[m][n] = __builtin_amdgcn_mfma_f32_16x16x32_bf16(af[m], bf[ks & 3][n], fzero(), 0, 0, 0);
      } else {
        #pragma unroll
        for (int m = 0; m < 4; ++m)
          #pragma unroll
          for (int n = 0; n < 4; ++n)
            cf[m][n] = __builtin_amdgcn_mfma_f32_16x16x32_bf16(af[m], bf[ks & 3][n], cf[m][n], 0, 0, 0);
      }
      __builtin_amdgcn_s_setprio(0);
      // prefetch slice s+4 into the slot just consumed (over-reads stay inside ws)
      #pragma unroll
      for (int n = 0; n < 4; ++n)
        bf[ks & 3][n] = *(const short8*)(bptr + (long)(s + 4) * 8192 + n * 512);
    }
    // epilogue: w = 3*tanh(pre) (odd poly, |pre| small), accT += xin[b,i] * w
    const int ig = i0 + ii;
    const bool isb = (ig == 256);
    f32x4 xv[4];
    if (isb) {
      #pragma unroll
      for (int m = 0; m < 4; ++m) { f32x4 o = {1.f,1.f,1.f,1.f}; xv[m] = o; }
    } else {
      #pragma unroll
      for (int m = 0; m < 4; ++m)
        xv[m] = *(const f32x4*)&xs[ii][m * 16 + lb * 4];
    }
    float b2v[4];
    #pragma unroll
    for (int n = 0; n < 4; ++n)
      b2v[n] = b2[(long)ig * 256 + c0 + n * 16 + la];
    #pragma unroll
    for (int m = 0; m < 4; ++m)
      #pragma unroll
      for (int n = 0; n < 4; ++n)
        #pragma unroll
        for (int r = 0; r < 4; ++r) {
          float pre = cf[m][n][r] + b2v[n];
          float t2 = pre * pre;
          float w = pre * fmaf(t2, fmaf(t2, fmaf(t2, -0.161905f, 0.4f), -1.0f), 3.0f);
          accT[m][n][r] = fmaf(xv[m][r], w, accT[m][n][r]);
        }
  }

  // non-temporal C-write: keep the 32MB 'part' stream out of the XCD L2
  float* dst = part + (long)islice * (4096 * 256);
  #pragma unroll
  for (int m = 0; m < 4; ++m)
    #pragma unroll
    for (int n = 0; n < 4; ++n)
      #pragma unroll
      for (int r = 0; r < 4; ++r)
        __builtin_nontemporal_store(accT[m][n][r],
            &dst[(long)(b0 + m * 16 + lb * 4 + r) * 256 + (c0 + n * 16 + la)]);
}

// ================= k_mid: redln (sum partials + LN2 + relu -> bf16) + Wc + bc ==========
__global__ void k_mid(const float* __restrict__ part, const float* __restrict__ g,
                      const float* __restrict__ b, u16* __restrict__ yb,
                      const float* __restrict__ wihf, const float* __restrict__ few,
                      u16* __restrict__ wcb,
                      const float* __restrict__ bih, const float* __restrict__ feb,
                      float* __restrict__ bcb) {
  const int bx = blockIdx.x, t = threadIdx.x;
  __shared__ float sm[256];
  if (bx < 4096) {                      // ---- redln ----
    float s = 0.f;
    #pragma unroll
    for (int sl = 0; sl < 8; ++sl) s += part[(long)sl * (4096 * 256) + (long)bx * 256 + t];
    float mu, inv; blk_ln(s, sm, t, mu, inv);
    float v = (s - mu) * inv * g[t] + b[t];
    yb[(long)bx * 256 + t] = f2b(fmaxf(v, 0.f));
    return;
  }
  if (bx < 4096 + 768) {                // ---- Wc[g,h] = sum_e wih[g,e]*few[e,h] -> bf16 ----
    int gg = bx - 4096;
    sm[t] = wihf[(long)gg * 256 + t];
    __syncthreads();
    float acc = 0.f;
    #pragma unroll 8
    for (int e = 0; e < 256; ++e) acc = fmaf(sm[e], few[(long)e * 256 + t], acc);
    wcb[(long)gg * 256 + t] = f2b(acc);
    return;
  }
  {                                     // ---- bc[g] = bih[g] + wih[g,:]·feb ----
    int gg = (bx - 4864) * 256 + t;
    float acc = bih[gg];
    const float* wr = wihf + (long)gg * 256;
    #pragma unroll 8
    for (int e = 0; e < 256; ++e) acc = fmaf(wr[e], feb[e], acc);
    bcb[gg] = acc;
  }
}

// ================= gemm256: C[M][N](f32) = A[M][256] @ B[N][256]^T + bias ==========
__device__ __forceinline__ void gemm256(const u16* __restrict__ Ab, const u16* __restrict__ Bb,
                                        const float* __restrict__ bias, float* __restrict__ Cf,
                                        int N, int ntiles, int blk, u16* As, u16* Bs) {
  const int t = threadIdx.x;
  const int mt = blk / ntiles, nt = blk % ntiles;
  const int m0 = mt * 128, n0 = nt * 128;
  const int lane = t & 63, wid = t >> 6;
  const int la = lane & 15, lb = lane >> 4;
  const int r0 = (wid >> 1) * 64, c0 = (wid & 1) * 64;
  f32x4 acc[4][4];
  #pragma unroll
  for (int m = 0; m < 4; ++m)
    #pragma unroll
    for (int n = 0; n < 4; ++n) acc[m][n] = fzero();
  for (int kh = 0; kh < 2; ++kh) {
    #pragma unroll
    for (int j = 0; j < 8; ++j) {
      int q = t + 256 * j;
      int row = q >> 4, cc = q & 15;
      *(u16x8*)&As[row * 136 + cc * 8] = *(const u16x8*)(Ab + (long)(m0 + row) * 256 + kh * 128 + cc * 8);
      *(u16x8*)&Bs[row * 136 + cc * 8] = *(const u16x8*)(Bb + (long)(n0 + row) * 256 + kh * 128 + cc * 8);
    }
    __syncthreads();
    #pragma unroll
    for (int ks = 0; ks < 4; ++ks) {
      short8 af[4], bf[4];
      #pragma unroll
      for (int m = 0; m < 4; ++m) af[m] = *(const short8*)&As[(r0 + m * 16 + la) * 136 + ks * 32 + lb * 8];
      #pragma unroll
      for (int n = 0; n < 4; ++n) bf[n] = *(const short8*)&Bs[(c0 + n * 16 + la) * 136 + ks * 32 + lb * 8];
      #pragma unroll
      for (int m = 0; m < 4; ++m)
        #pragma unroll
        for (int n = 0; n < 4; ++n)
          acc[m][n] = __builtin_amdgcn_mfma_f32_16x16x32_bf16(af[m], bf[n], acc[m][n], 0, 0, 0);
    }
    __syncthreads();
  }
  #pragma unroll
  for (int n = 0; n < 4; ++n) {
    int gc = n0 + c0 + n * 16 + la;
    float bv = bias[gc];
    #pragma unroll
    for (int m = 0; m < 4; ++m) {
      int gr = m0 + r0 + m * 16 + lb * 4;
      #pragma unroll
      for (int r = 0; r < 4; ++r)
        Cf[(long)(gr + r) * N + gc] = acc[m][n][r] + bv;
    }
  }
}

// ================= k_gigh: gi = yb@Wc^T + bc ; gh = hidb@whh^T + bhh ==========
__global__ __launch_bounds__(256) void k_gigh(const u16* __restrict__ yb, const u16* __restrict__ wcb,
                                              const float* __restrict__ bcb,
                                              const u16* __restrict__ hidb, const u16* __restrict__ whhb,
                                              const float* __restrict__ bhh,
                                              float* __restrict__ gim, float* __restrict__ ghm) {
  __shared__ u16 smem[2 * 128 * 136];
  const int bx = blockIdx.x;
  if (bx < 192) gemm256(yb,   wcb,  bcb, gim, 768, 6, bx,       smem, smem + 128 * 136);
  else          gemm256(hidb, whhb, bhh, ghm, 768, 6, bx - 192, smem, smem + 128 * 136);
}

// ================= k_gru: GRU cell + dueling heads =================
__global__ void k_gru(const float* __restrict__ gi, const float* __restrict__ gh,
                      const float* __restrict__ hin,
                      const float* __restrict__ vw, const float* __restrict__ vb,
                      const float* __restrict__ aw, const float* __restrict__ ab,
                      float* __restrict__ qout, float* __restrict__ hout) {
  int bb = blockIdx.x, t = threadIdx.x;
  const float* gib = gi + (long)bb * 768;
  const float* ghb = gh + (long)bb * 768;
  float ir = gib[t], iz = gib[256 + t], inx = gib[512 + t];
  float hr = ghb[t], hz = ghb[256 + t], hn = ghb[512 + t];
  float hprev = hin[(long)bb * 256 + t];
  float r = 1.f / (1.f + expf(-(ir + hr)));
  float z = 1.f / (1.f + expf(-(iz + hz)));
  float n = tanhf(inx + r * hn);
  float h = (1.f - z) * n + z * hprev;
  hout[(long)bb * 256 + t] = h;
  __shared__ float hl[256];
  __shared__ float ov[32];
  __shared__ float mred;
  hl[t] = h;
  __syncthreads();
  int gidx = t >> 3, lg = t & 7;
  if (gidx < 31) {
    const float* wr = (gidx < 30) ? (aw + (long)gidx * 256) : vw;
    float p = 0.f;
    #pragma unroll 8
    for (int j = 0; j < 32; ++j) p += hl[lg + 8 * j] * wr[lg + 8 * j];
    p += __shfl_xor(p, 1); p += __shfl_xor(p, 2); p += __shfl_xor(p, 4);
    if (lg == 0) ov[gidx] = p + ((gidx < 30) ? ab[gidx] : vb[0]);
  }
  __syncthreads();
  if (t == 0) {
    float m = 0.f;
    #pragma unroll
    for (int a = 0; a < 30; ++a) m += ov[a];
    mred = m * (1.f / 30.f);
  }
  __syncthreads();
  if (t < 30) qout[(long)bb * 30 + t] = ov[30] + ov[t] - mred;
}

// ================= launch =================
extern "C" void kernel_launch(void* const* d_in, const int* in_sizes, int n_in,
                              void* d_out, int out_size, void* d_ws, size_t ws_size,
                              hipStream_t stream) {
  const float* inputs = (const float*)d_in[0];
  const float* hidden = (const float*)d_in[1];
  const float* goal   = (const float*)d_in[2];
  const float* ln1g   = (const float*)d_in[3];
  const float* ln1b   = (const float*)d_in[4];
  const float* hyw1   = (const float*)d_in[5];
  const float* hyb1   = (const float*)d_in[6];
  const float* hyw2   = (const float*)d_in[7];
  const float* hyb2   = (const float*)d_in[8];
  const float* ln2g   = (const float*)d_in[9];
  const float* ln2b   = (const float*)d_in[10];
  const float* few    = (const float*)d_in[11];
  const float* feb    = (const float*)d_in[12];
  const float* wih    = (const float*)d_in[13];
  const float* whh    = (const float*)d_in[14];
  const float* bih    = (const float*)d_in[15];
  const float* bhh    = (const float*)d_in[16];
  const float* valw   = (const float*)d_in[17];
  const float* valb   = (const float*)d_in[18];
  const float* advw   = (const float*)d_in[19];
  const float* advb   = (const float*)d_in[20];

  char* ws = (char*)d_ws;
  u16* w2b   = (u16*)(ws + OFF_W2B);
  u16* hidb  = (u16*)(ws + OFF_HIDB);
  u16* fwbT  = (u16*)(ws + OFF_FWT);
  u16* wihb  = (u16*)(ws + OFF_WIHB);
  u16* whhb  = (u16*)(ws + OFF_WHHB);
  u16* h1b   = (u16*)(ws + OFF_H1B);
  float* xin = (float*)(ws + OFF_XIN);
  u16* yb    = (u16*)(ws + OFF_XIN);                 // aliases xin (dead after k_big)
  u16* wcb   = (u16*)(ws + OFF_WCB);
  float* bcb = (float*)(ws + OFF_BCB);
  float* prt = (float*)(ws + OFF_PART);
  float* gim = (float*)(ws + OFF_PART);              // aliases part (dead after k_mid)
  float* ghm = (float*)(ws + OFF_PART + 12582912UL);
  float* qout = (float*)d_out;
  float* hout = qout + (long)BS * A_;

  k_pre<<<NB_PRE, 256, 0, stream>>>(hyw2, hidden, few, wih, whh,
                                    inputs, ln1g, ln1b, goal, hyw1, hyb1,
                                    w2b, hidb, fwbT, wihb, whhb, xin, h1b);
  k_big<<<512, 256, 0, stream>>>(w2b, h1b, xin, hyb2, prt);
  k_mid<<<4867, 256, 0, stream>>>(prt, ln2g, ln2b, yb, wih, few, wcb, bih, feb, bcb);
  k_gigh<<<384, 256, 0, stream>>>(yb, wcb, bcb, hidb, whhb, bhh, gim, ghm);
  k_gru<<<4096, 256, 0, stream>>>(gim, ghm, hidden, valw, valb, advw, advb, qout, hout);
}

// Round 4
// 367.641 us; speedup vs baseline: 1.6756x; 1.0231x over previous
//
#include <hip/hip_runtime.h>
#include <hip/hip_bf16.h>

// ---------- types ----------
typedef unsigned short u16;
typedef __attribute__((ext_vector_type(4))) float f32x4;
typedef __attribute__((ext_vector_type(8))) short short8;   // 8 bf16 for MFMA operands
typedef __attribute__((ext_vector_type(8))) u16 u16x8;

__device__ __forceinline__ f32x4 fzero() { f32x4 z = {0.f, 0.f, 0.f, 0.f}; return z; }

// f32 -> bf16 bits, round-to-nearest-even
__device__ __forceinline__ u16 f2b(float x) {
  unsigned u = __builtin_bit_cast(unsigned, x);
  unsigned r = (u + 0x7fffu + ((u >> 16) & 1u)) >> 16;
  return (u16)r;
}

// ---------- problem constants ----------
#define BS 4096
#define A_ 30

// ---------- ws offsets (bytes) ----------
#define OFF_W2B   0UL            // 33,685,504  (2056 slices x 16KB, frag-order)
#define OFF_H1B   33685504UL     //  2,097,152
#define OFF_XIN   35782656UL     //  4,194,304
#define OFF_WCFR  39976960UL     //    393,216  (Wc = wih@few, frag-order)
#define OFF_WHFR  40370176UL     //    393,216  (whh, frag-order)
#define OFF_BC    40763392UL     //      3,072  (bc = bih + wih@feb)
#define OFF_PART  40766464UL     // 33,554,432
// end 74,320,896

#define NC_W2   2105344L
#define NB_W2   8224
#define NB_WHH  96
#define NB_LN1  4096
#define NB_H1   4096
#define NB_WC   768
#define NB_PRE  (NB_W2 + NB_WHH + NB_LN1 + NB_H1 + NB_WC)   // 17280

// ================= block-wide mean/inv-std over 256 elems (256 thr) =================
__device__ __forceinline__ void blk_ln(float v, float* red, int t, float& mu, float& inv) {
  float s = v, sq = v * v;
  #pragma unroll
  for (int o = 32; o; o >>= 1) { s += __shfl_xor(s, o); sq += __shfl_xor(sq, o); }
  int w = t >> 6;
  if ((t & 63) == 0) { red[w] = s; red[4 + w] = sq; }
  __syncthreads();
  float S = red[0] + red[1] + red[2] + red[3];
  float Q = red[4] + red[5] + red[6] + red[7];
  mu = S * (1.f / 256.f);
  float var = Q * (1.f / 256.f) - mu * mu;
  inv = rsqrtf(var + 1e-5f);
  __syncthreads();
}

// ================= k_pre: conversions + ln1 + h1 + Wc/bc =================
// w2b frag layout: dst[((i*8+ks)*256 + h)*32 + kk] = hy_w2[i*256+h][ks*32+kk]
// whfr/wcfr frag layout: dst[(ks*768 + g)*32 + kk] = W[g][ks*32+kk]
__global__ void k_pre(const float* __restrict__ hyw2, const float* __restrict__ whh,
                      const float* __restrict__ inp,  const float* __restrict__ ln1g,
                      const float* __restrict__ ln1b,
                      const float* __restrict__ goal, const float* __restrict__ hyw1,
                      const float* __restrict__ hyb1,
                      const float* __restrict__ wih,  const float* __restrict__ few,
                      const float* __restrict__ feb,  const float* __restrict__ bih,
                      u16* __restrict__ w2b, u16* __restrict__ whfr,
                      float* __restrict__ xin, u16* __restrict__ h1b,
                      u16* __restrict__ wcfr, float* __restrict__ bcv) {
  const int bx = blockIdx.x, t = threadIdx.x;
  __shared__ float sm[256];
  __shared__ float red[8];

  if (bx < NB_W2) {                       // ---- w2 -> bf16 frag slices ----
    long c = (long)bx * 256 + t;
    long d = c * 8;
    int kk0 = (int)((c & 3) * 8);
    int h   = (int)((c >> 2) & 255);
    long s  = c >> 10;                    // slice 0..2055
    int ks  = (int)(s & 7);
    long i  = s >> 3;                     // 0..256 (i==256 -> bias rows)
    const float* src = hyw2 + (i * 256 + h) * 256 + ks * 32 + kk0;
    f32x4 a = *(const f32x4*)src;
    f32x4 b = *(const f32x4*)(src + 4);
    u16x8 o;
    o[0]=f2b(a[0]); o[1]=f2b(a[1]); o[2]=f2b(a[2]); o[3]=f2b(a[3]);
    o[4]=f2b(b[0]); o[5]=f2b(b[1]); o[6]=f2b(b[2]); o[7]=f2b(b[3]);
    *(u16x8*)(w2b + d) = o;
    return;
  }
  if (bx < NB_W2 + NB_WHH) {              // ---- whh -> bf16 frag layout ----
    int c = (bx - NB_W2) * 256 + t;       // 0..24575
    int ks = c / 3072, rem = c - ks * 3072;
    int g = rem >> 2, kk0 = (rem & 3) * 8;
    const float* src = whh + (long)g * 256 + ks * 32 + kk0;
    f32x4 a = *(const f32x4*)src;
    f32x4 b = *(const f32x4*)(src + 4);
    u16x8 o;
    o[0]=f2b(a[0]); o[1]=f2b(a[1]); o[2]=f2b(a[2]); o[3]=f2b(a[3]);
    o[4]=f2b(b[0]); o[5]=f2b(b[1]); o[6]=f2b(b[2]); o[7]=f2b(b[3]);
    *(u16x8*)(whfr + ((long)ks * 768 + g) * 32 + kk0) = o;
    return;
  }
  if (bx < NB_W2 + NB_WHH + NB_LN1) {     // ---- ln1 ----
    int bb = bx - (NB_W2 + NB_WHH);
    float v = inp[(long)bb * 256 + t];
    float mu, inv; blk_ln(v, red, t, mu, inv);
    xin[(long)bb * 256 + t] = (v - mu) * inv * ln1g[t] + ln1b[t];
    return;
  }
  if (bx < NB_W2 + NB_WHH + NB_LN1 + NB_H1) {   // ---- h1 ----
    int bb = bx - (NB_W2 + NB_WHH + NB_LN1);
    if (t < 64) sm[t] = goal[(long)bb * 64 + t];
    __syncthreads();
    const float* wr = hyw1 + (long)t * 64;
    float acc = hyb1[t];
    #pragma unroll
    for (int g4 = 0; g4 < 16; ++g4) {
      f32x4 w = *(const f32x4*)(wr + g4 * 4);
      acc = fmaf(sm[g4*4+0], w[0], acc);
      acc = fmaf(sm[g4*4+1], w[1], acc);
      acc = fmaf(sm[g4*4+2], w[2], acc);
      acc = fmaf(sm[g4*4+3], w[3], acc);
    }
    h1b[(long)bb * 256 + t] = f2b(fmaxf(acc, 0.f));
    return;
  }
  {                                       // ---- Wc row gg (frag layout) + bc[gg] ----
    int gg = bx - (NB_W2 + NB_WHH + NB_LN1 + NB_H1);
    sm[t] = wih[(long)gg * 256 + t];
    __syncthreads();
    float acc = 0.f;
    #pragma unroll 8
    for (int e = 0; e < 256; ++e) acc = fmaf(sm[e], few[(long)e * 256 + t], acc);
    wcfr[((long)(t >> 5) * 768 + gg) * 32 + (t & 31)] = f2b(acc);
    // bc[gg] = bih[gg] + wih[gg,:]·feb
    float p = sm[t] * feb[t];
    #pragma unroll
    for (int o = 32; o; o >>= 1) p += __shfl_xor(p, o);
    if ((t & 63) == 0) red[t >> 6] = p;
    __syncthreads();
    if (t == 0) bcv[gg] = bih[gg] + red[0] + red[1] + red[2] + red[3];
  }
}

// ================= k_big: fused hypernet GEMM + tanh*3 + contraction ==========
// grid 512 = 64 btiles x 8 islices (islice = bx&7 -> XCD-pinned 4.2MB w2 chunk).
// B streams global->VGPR (frag-order, coalesced), 4-deep register ring.
// ONE rhythm barrier per ii (not per ks): compiler free to pipeline the 8 steps'
// ds_reads + B prefetches; block progress rates stay matched; NT part stores
// keep the w2 stream resident in L2.
__global__ __launch_bounds__(256, 2) void k_big(const u16* __restrict__ w2b,
                                                const u16* __restrict__ h1b,
                                                const float* __restrict__ xin,
                                                const float* __restrict__ b2,
                                                float* __restrict__ part) {
  const int bx = blockIdx.x;
  const int islice = bx & 7, btile = bx >> 3;
  const int b0 = btile * 64, i0 = islice * 32;
  const int ni = (islice == 7) ? 33 : 32;   // islice 7 adds the bias row-block (i==256)
  const int t = threadIdx.x, lane = t & 63, wid = t >> 6;
  const int la = lane & 15, lb = lane >> 4;
  const int c0 = wid * 64;

  __shared__ u16 As[64 * 264];      // h1 tile, pitch 264 (2-way bank spread = free)
  __shared__ float xs[32][64];      // xin slice [ii][row]

  #pragma unroll
  for (int j = 0; j < 8; ++j) {
    int q = t + 256 * j;
    int row = q >> 5, cc = q & 31;
    *(u16x8*)&As[row * 264 + cc * 8] = *(const u16x8*)(h1b + (long)(b0 + row) * 256 + cc * 8);
  }
  {
    int row = t >> 2, part4 = t & 3;
    const float* src = xin + (long)(b0 + row) * 256 + i0 + part4 * 8;
    f32x4 v0 = *(const f32x4*)src;
    f32x4 v1 = *(const f32x4*)(src + 4);
    #pragma unroll
    for (int j = 0; j < 4; ++j) xs[part4 * 8 + j][row] = v0[j];
    #pragma unroll
    for (int j = 0; j < 4; ++j) xs[part4 * 8 + 4 + j][row] = v1[j];
  }
  __syncthreads();

  const u16* bptr = w2b + (long)i0 * 8 * 8192 + (c0 + la) * 32 + lb * 8;
  const int lds_a = la * 528 + lb * 16;   // byte offset into As

  f32x4 accT[4][4];
  #pragma unroll
  for (int m = 0; m < 4; ++m)
    #pragma unroll
    for (int n = 0; n < 4; ++n) accT[m][n] = fzero();

  short8 bf[4][4];   // [slot][n] — 4-deep register prefetch ring
  #pragma unroll
  for (int s = 0; s < 4; ++s)
    #pragma unroll
    for (int n = 0; n < 4; ++n)
      bf[s][n] = *(const short8*)(bptr + (long)s * 8192 + n * 512);

  for (int ii = 0; ii < ni; ++ii) {
    __builtin_amdgcn_s_barrier();   // per-ii rhythm barrier (no vmcnt drain)
    const int ig = i0 + ii;
    const bool isb = (ig == 256);
    // hoisted per-ii operands (available by epilogue time)
    f32x4 xv[4];
    if (isb) {
      #pragma unroll
      for (int m = 0; m < 4; ++m) { f32x4 o = {1.f,1.f,1.f,1.f}; xv[m] = o; }
    } else {
      #pragma unroll
      for (int m = 0; m < 4; ++m)
        xv[m] = *(const f32x4*)&xs[ii][m * 16 + lb * 4];
    }
    float b2v[4];
    #pragma unroll
    for (int n = 0; n < 4; ++n)
      b2v[n] = b2[(long)ig * 256 + c0 + n * 16 + la];

    f32x4 cf[4][4];
    #pragma unroll
    for (int ks = 0; ks < 8; ++ks) {
      const int s = ii * 8 + ks;
      short8 af[4];
      #pragma unroll
      for (int m = 0; m < 4; ++m)
        af[m] = *(const short8*)((const char*)As + lds_a + m * 8448 + ks * 64);
      __builtin_amdgcn_s_setprio(1);
      if (ks == 0) {
        #pragma unroll
        for (int m = 0; m < 4; ++m)
          #pragma unroll
          for (int n = 0; n < 4; ++n)
            cf[m][n] = __builtin_amdgcn_mfma_f32_16x16x32_bf16(af[m], bf[ks & 3][n], fzero(), 0, 0, 0);
      } else {
        #pragma unroll
        for (int m = 0; m < 4; ++m)
          #pragma unroll
          for (int n = 0; n < 4; ++n)
            cf[m][n] = __builtin_amdgcn_mfma_f32_16x16x32_bf16(af[m], bf[ks & 3][n], cf[m][n], 0, 0, 0);
      }
      __builtin_amdgcn_s_setprio(0);
      // prefetch slice s+4 into the slot just consumed (over-reads stay inside ws)
      #pragma unroll
      for (int n = 0; n < 4; ++n)
        bf[ks & 3][n] = *(const short8*)(bptr + (long)(s + 4) * 8192 + n * 512);
    }
    // epilogue: w = 3*tanh(pre) (odd poly, |pre| <= ~0.6), accT += x_in[b,i]*w
    #pragma unroll
    for (int m = 0; m < 4; ++m)
      #pragma unroll
      for (int n = 0; n < 4; ++n)
        #pragma unroll
        for (int r = 0; r < 4; ++r) {
          float pre = cf[m][n][r] + b2v[n];
          float t2 = pre * pre;
          float w = pre * fmaf(t2, fmaf(t2, fmaf(t2, -0.161905f, 0.4f), -1.0f), 3.0f);
          accT[m][n][r] = fmaf(xv[m][r], w, accT[m][n][r]);
        }
  }

  // non-temporal C-write: keep the 32MB 'part' stream out of the XCD L2
  float* dst = part + (long)islice * (4096 * 256);
  #pragma unroll
  for (int m = 0; m < 4; ++m)
    #pragma unroll
    for (int n = 0; n < 4; ++n)
      #pragma unroll
      for (int r = 0; r < 4; ++r)
        __builtin_nontemporal_store(accT[m][n][r],
            &dst[(long)(b0 + m * 16 + lb * 4 + r) * 256 + (c0 + n * 16 + la)]);
}

// ================= k_post: redln + (gi,gh) MFMA + GRU + dueling heads ==========
// grid 256 blocks x 16 rows. Everything after k_big is row-local once Wc/bc exist.
// yb lives only in LDS; B (wcfr/whfr, 786KB) streams from L2 in frag order.
__global__ __launch_bounds__(256) void k_post(const float* __restrict__ part,
                                              const float* __restrict__ ln2g,
                                              const float* __restrict__ ln2b,
                                              const u16* __restrict__ wcfr,
                                              const u16* __restrict__ whfr,
                                              const float* __restrict__ bcv,
                                              const float* __restrict__ bhh,
                                              const float* __restrict__ hidden,
                                              const float* __restrict__ advw,
                                              const float* __restrict__ advb,
                                              const float* __restrict__ valw,
                                              const float* __restrict__ valb,
                                              float* __restrict__ qout,
                                              float* __restrict__ hout) {
  const int bx = blockIdx.x, t = threadIdx.x;
  const int b0 = bx * 16;
  __shared__ u16 ya[16 * 264];     // relu(LN2) tile, A-frag friendly
  __shared__ u16 ha[16 * 264];     // hidden bf16 tile
  __shared__ float hs[16 * 264];   // h (f32) for heads
  __shared__ float ov[16][33];
  __shared__ float ms[16];

  // ---- phase 1: redln -> ya ----
  {
    const int r = t >> 4, ch = (t & 15) * 16;
    const float* pb = part + (long)(b0 + r) * 256 + ch;
    f32x4 s4[4];
    #pragma unroll
    for (int q = 0; q < 4; ++q) s4[q] = fzero();
    #pragma unroll
    for (int sl = 0; sl < 8; ++sl) {
      const f32x4* ps = (const f32x4*)(pb + (long)sl * (4096 * 256));
      #pragma unroll
      for (int q = 0; q < 4; ++q) {
        f32x4 v = __builtin_nontemporal_load(ps + q);
        s4[q] += v;
      }
    }
    float sv = 0.f, sq = 0.f;
    #pragma unroll
    for (int q = 0; q < 4; ++q)
      #pragma unroll
      for (int j = 0; j < 4; ++j) { float v = s4[q][j]; sv += v; sq += v * v; }
    #pragma unroll
    for (int o = 1; o < 16; o <<= 1) { sv += __shfl_xor(sv, o); sq += __shfl_xor(sq, o); }
    float mu = sv * (1.f / 256.f);
    float inv = rsqrtf(sq * (1.f / 256.f) - mu * mu + 1e-5f);
    u16x8 o0, o1;
    #pragma unroll
    for (int q = 0; q < 4; ++q)
      #pragma unroll
      for (int j = 0; j < 4; ++j) {
        int c = ch + q * 4 + j;
        float v = (s4[q][j] - mu) * inv * ln2g[c] + ln2b[c];
        v = fmaxf(v, 0.f);
        if (q < 2) o0[q * 4 + j] = f2b(v); else o1[(q - 2) * 4 + j] = f2b(v);
      }
    *(u16x8*)&ya[r * 264 + ch] = o0;
    *(u16x8*)&ya[r * 264 + ch + 8] = o1;
  }
  // ---- phase 1b: hidden -> ha (bf16) ----
  {
    const int r = t >> 4, ch = (t & 15) * 16;
    const float* hp = hidden + (long)(b0 + r) * 256 + ch;
    u16x8 o0, o1;
    #pragma unroll
    for (int j = 0; j < 8; ++j) o0[j] = f2b(hp[j]);
    #pragma unroll
    for (int j = 0; j < 8; ++j) o1[j] = f2b(hp[8 + j]);
    *(u16x8*)&ha[r * 264 + ch] = o0;
    *(u16x8*)&ha[r * 264 + ch + 8] = o1;
  }
  __syncthreads();

  // ---- phase 2: GEMM (r,z fused across gi+gh; n split) ----
  const int lane = t & 63, wid = t >> 6;
  const int la = lane & 15, lb = lane >> 4;
  const int c0w = wid * 64;
  f32x4 aR[4], aZ[4], aN[4], aH[4];
  #pragma unroll
  for (int n = 0; n < 4; ++n) { aR[n] = fzero(); aZ[n] = fzero(); aN[n] = fzero(); aH[n] = fzero(); }
  #pragma unroll
  for (int ks = 0; ks < 8; ++ks) {
    short8 ay = *(const short8*)&ya[la * 264 + ks * 32 + lb * 8];
    short8 ah = *(const short8*)&ha[la * 264 + ks * 32 + lb * 8];
    #pragma unroll
    for (int n = 0; n < 4; ++n) {
      const int c = c0w + n * 16 + la;
      const u16* wp = wcfr + ((long)ks * 768 + c) * 32 + lb * 8;
      const u16* hp = whfr + ((long)ks * 768 + c) * 32 + lb * 8;
      short8 bWr = *(const short8*)wp;
      short8 bWz = *(const short8*)(wp + 256 * 32);
      short8 bWn = *(const short8*)(wp + 512 * 32);
      short8 bHr = *(const short8*)hp;
      short8 bHz = *(const short8*)(hp + 256 * 32);
      short8 bHn = *(const short8*)(hp + 512 * 32);
      aR[n] = __builtin_amdgcn_mfma_f32_16x16x32_bf16(ay, bWr, aR[n], 0, 0, 0);
      aR[n] = __builtin_amdgcn_mfma_f32_16x16x32_bf16(ah, bHr, aR[n], 0, 0, 0);
      aZ[n] = __builtin_amdgcn_mfma_f32_16x16x32_bf16(ay, bWz, aZ[n], 0, 0, 0);
      aZ[n] = __builtin_amdgcn_mfma_f32_16x16x32_bf16(ah, bHz, aZ[n], 0, 0, 0);
      aN[n] = __builtin_amdgcn_mfma_f32_16x16x32_bf16(ay, bWn, aN[n], 0, 0, 0);
      aH[n] = __builtin_amdgcn_mfma_f32_16x16x32_bf16(ah, bHn, aH[n], 0, 0, 0);
    }
  }

  // ---- phase 3: GRU elementwise ----
  #pragma unroll
  for (int n = 0; n < 4; ++n) {
    const int c = c0w + n * 16 + la;
    float bcr = bcv[c], bcz = bcv[c + 256], bcn = bcv[c + 512];
    float bhr = bhh[c], bhz = bhh[c + 256], bhn = bhh[c + 512];
    #pragma unroll
    for (int jr = 0; jr < 4; ++jr) {
      const int row = lb * 4 + jr;
      const long gb = (long)(b0 + row) * 256 + c;
      float rr = 1.f / (1.f + expf(-(aR[n][jr] + bcr + bhr)));
      float zz = 1.f / (1.f + expf(-(aZ[n][jr] + bcz + bhz)));
      float nn = tanhf(aN[n][jr] + bcn + rr * (aH[n][jr] + bhn));
      float hp = hidden[gb];
      float h = (1.f - zz) * nn + zz * hp;
      hout[gb] = h;
      hs[row * 264 + c] = h;
    }
  }
  __syncthreads();

  // ---- phase 4: dueling heads ----
  {
    const int out = t >> 3, lg = t & 7;          // 32 out-groups x 8 lanes
    if (out < 31) {
      const float* wr = (out < 30) ? (advw + (long)out * 256) : valw;
      for (int r = 0; r < 16; ++r) {
        float p = 0.f;
        #pragma unroll 8
        for (int j = 0; j < 32; ++j) p += hs[r * 264 + lg + 8 * j] * wr[lg + 8 * j];
        p += __shfl_xor(p, 1); p += __shfl_xor(p, 2); p += __shfl_xor(p, 4);
        if (lg == 0) ov[r][out] = p + ((out < 30) ? advb[out] : valb[0]);
      }
    }
  }
  __syncthreads();
  {
    const int r = t >> 4, o = t & 15;
    if (o == 0) {
      float m = 0.f;
      #pragma unroll
      for (int a = 0; a < 30; ++a) m += ov[r][a];
      ms[r] = m * (1.f / 30.f);
    }
  }
  __syncthreads();
  {
    const int r = t >> 4, o = t & 15;
    if (o < 15) {
      float vv = ov[r][30], mm = ms[r];
      qout[(long)(b0 + r) * 30 + o]      = vv + ov[r][o]      - mm;
      qout[(long)(b0 + r) * 30 + o + 15] = vv + ov[r][o + 15] - mm;
    }
  }
}

// ================= launch =================
extern "C" void kernel_launch(void* const* d_in, const int* in_sizes, int n_in,
                              void* d_out, int out_size, void* d_ws, size_t ws_size,
                              hipStream_t stream) {
  const float* inputs = (const float*)d_in[0];
  const float* hidden = (const float*)d_in[1];
  const float* goal   = (const float*)d_in[2];
  const float* ln1g   = (const float*)d_in[3];
  const float* ln1b   = (const float*)d_in[4];
  const float* hyw1   = (const float*)d_in[5];
  const float* hyb1   = (const float*)d_in[6];
  const float* hyw2   = (const float*)d_in[7];
  const float* hyb2   = (const float*)d_in[8];
  const float* ln2g   = (const float*)d_in[9];
  const float* ln2b   = (const float*)d_in[10];
  const float* few    = (const float*)d_in[11];
  const float* feb    = (const float*)d_in[12];
  const float* wih    = (const float*)d_in[13];
  const float* whh    = (const float*)d_in[14];
  const float* bih    = (const float*)d_in[15];
  const float* bhh    = (const float*)d_in[16];
  const float* valw   = (const float*)d_in[17];
  const float* valb   = (const float*)d_in[18];
  const float* advw   = (const float*)d_in[19];
  const float* advb   = (const float*)d_in[20];

  char* ws = (char*)d_ws;
  u16* w2b    = (u16*)(ws + OFF_W2B);
  u16* h1b    = (u16*)(ws + OFF_H1B);
  float* xin  = (float*)(ws + OFF_XIN);
  u16* wcfr   = (u16*)(ws + OFF_WCFR);
  u16* whfr   = (u16*)(ws + OFF_WHFR);
  float* bcv  = (float*)(ws + OFF_BC);
  float* prt  = (float*)(ws + OFF_PART);
  float* qout = (float*)d_out;
  float* hout = qout + (long)BS * A_;

  k_pre<<<NB_PRE, 256, 0, stream>>>(hyw2, whh, inputs, ln1g, ln1b, goal, hyw1, hyb1,
                                    wih, few, feb, bih,
                                    w2b, whfr, xin, h1b, wcfr, bcv);
  k_big<<<512, 256, 0, stream>>>(w2b, h1b, xin, hyb2, prt);
  k_post<<<256, 256, 0, stream>>>(prt, ln2g, ln2b, wcfr, whfr, bcv, bhh, hidden,
                                  advw, advb, valw, valb, qout, hout);
}